// Round 7
// baseline (299.569 us; speedup 1.0000x reference)
//
#include <hip/hip_runtime.h>

#define B_ 4
#define T_ 2048
#define D_ 1024
#define H_ 16
#define S_ 64

typedef __attribute__((ext_vector_type(8))) short bf16x8;
typedef __attribute__((ext_vector_type(16))) float f32x16;
typedef unsigned int uint;

__device__ __forceinline__ short f2bf(float f) {
    union { float f; uint u; } v; v.f = f;
    uint r = v.u + 0x7fffu + ((v.u >> 16) & 1u);   // RNE
    return (short)(r >> 16);
}

// async global->LDS, 16B per lane; LDS dst = wave-uniform base + lane*16
__device__ __forceinline__ void gld16(const short* g, short* l) {
    __builtin_amdgcn_global_load_lds((const __attribute__((address_space(1))) void*)g,
                                     (__attribute__((address_space(3))) void*)l, 16, 0, 0);
}

// ---------------- fused fp32->bf16 prepass: x, Wq, Wu ----------------
__global__ __launch_bounds__(256) void cvt3(const float* __restrict__ x,
                                            const float* __restrict__ wq,
                                            const float* __restrict__ wu,
                                            short* __restrict__ xb,
                                            short* __restrict__ wqb,
                                            short* __restrict__ wub) {
    const int NX = B_ * T_ * D_ / 8;
    const int NW = D_ * D_ / 8;
    int i = blockIdx.x * 256 + threadIdx.x;
    const float* src; short* dst; int off;
    if (i < NX)            { src = x;  dst = xb;  off = i; }
    else if (i < NX + NW)  { src = wq; dst = wqb; off = i - NX; }
    else                   { src = wu; dst = wub; off = i - NX - NW; }
    float4 a = *(const float4*)(src + (size_t)off * 8);
    float4 b = *(const float4*)(src + (size_t)off * 8 + 4);
    short o[8] = {f2bf(a.x), f2bf(a.y), f2bf(a.z), f2bf(a.w),
                  f2bf(b.x), f2bf(b.y), f2bf(b.z), f2bf(b.w)};
    *(bf16x8*)(dst + (size_t)off * 8) = *(bf16x8*)o;
}

// ---------------- transpose q -> qT with swap23 baked in ----------------
// qT[bh][s][p] = q[b][t0+pi(p)][hh*64+s]  where pi swaps bits2<->3 within 16.
// pi baked in so attn's PV B-fragments are single contiguous b128 reads.
__global__ __launch_bounds__(256) void transp(const short* __restrict__ q,
                                              short* __restrict__ qT) {
    __shared__ short L[64 * 68];              // [s][t] pad 68
    const int tid = threadIdx.x;
    const int bh = blockIdx.y;
    const int t0 = blockIdx.x * 64;
    const short* qh = q + (size_t)(bh >> 4) * (T_ * D_) + (bh & 15) * S_;
    #pragma unroll
    for (int rep = 0; rep < 2; ++rep) {
        int f = rep * 256 + tid;
        int r = f >> 3, c8 = f & 7;
        bf16x8 v = *(const bf16x8*)(qh + (size_t)(t0 + r) * D_ + c8 * 8);
        short sv[8]; *(bf16x8*)sv = v;
        #pragma unroll
        for (int ds = 0; ds < 8; ++ds)
            L[(c8 * 8 + ds) * 68 + r] = sv[ds];
    }
    __syncthreads();
    #pragma unroll
    for (int rep = 0; rep < 2; ++rep) {
        int f = rep * 256 + tid;
        int s = f >> 3, pc = f & 7;
        int bt = (pc >> 1) * 16 + (pc & 1) * 4;     // pi: run0 = bt+0..3, run1 = bt+8..11
        short o[8];
        #pragma unroll
        for (int j = 0; j < 4; ++j) o[j]     = L[s * 68 + bt + j];
        #pragma unroll
        for (int j = 0; j < 4; ++j) o[4 + j] = L[s * 68 + bt + 8 + j];
        *(bf16x8*)(qT + ((size_t)bh * S_ + s) * T_ + t0 + pc * 8) = *(bf16x8*)o;
    }
}

// ---------------- bf16 MFMA GEMM, double-buffered global_load_lds ----------
// C[M,N] = A[M,K] @ Bt[N,K]^T. 128x128 tile, BK=32, 4 waves (2x2).
// Prefetch for tile i+1 issued AFTER the barrier -> vmcnt drain at next
// barrier lands a full compute-block later (real pipelining).
template <bool OUT_BF16>
__global__ __launch_bounds__(256, 2) void gemm_bt(const short* __restrict__ A,
                                                  const short* __restrict__ Bt,
                                                  const float* __restrict__ bias,
                                                  void* __restrict__ Cv,
                                                  int M, int N, int K, float oscale) {
    __shared__ short As[2][4096];   // 16 KB
    __shared__ short Bs[2][4096];   // 16 KB
    const int tid  = threadIdx.x;
    const int lane = tid & 63;
    const int wv   = tid >> 6;
    const int wm   = wv >> 1, wn = wv & 1;
    const int h32  = lane >> 5;
    const int m0 = blockIdx.y * 128, n0 = blockIdx.x * 128;
    const short* Ap = A + (size_t)m0 * K;
    const short* Bp = Bt + (size_t)n0 * K;

    f32x16 acc[2][2];
    #pragma unroll
    for (int i = 0; i < 2; ++i)
        #pragma unroll
        for (int j = 0; j < 2; ++j)
            #pragma unroll
            for (int r = 0; r < 16; ++r) acc[i][j][r] = 0.f;

    // preload tile 0 -> buf 0
    gld16(Ap + (size_t)lane * K        + wv * 8, &As[0][(wv * 128) * 8]);
    gld16(Ap + (size_t)(64 + lane) * K + wv * 8, &As[0][(wv * 128 + 64) * 8]);
    gld16(Bp + (size_t)lane * K        + wv * 8, &Bs[0][(wv * 128) * 8]);
    gld16(Bp + (size_t)(64 + lane) * K + wv * 8, &Bs[0][(wv * 128 + 64) * 8]);
    __syncthreads();

    int p = 0;
    for (int k0 = 0; k0 < K; k0 += 32) {
        if (k0 + 32 < K) {   // prefetch next tile into 1-p (in flight during compute)
            int kn = k0 + 32;
            gld16(Ap + (size_t)lane * K        + kn + wv * 8, &As[1 - p][(wv * 128) * 8]);
            gld16(Ap + (size_t)(64 + lane) * K + kn + wv * 8, &As[1 - p][(wv * 128 + 64) * 8]);
            gld16(Bp + (size_t)lane * K        + kn + wv * 8, &Bs[1 - p][(wv * 128) * 8]);
            gld16(Bp + (size_t)(64 + lane) * K + kn + wv * 8, &Bs[1 - p][(wv * 128 + 64) * 8]);
        }
        #pragma unroll
        for (int ks2 = 0; ks2 < 2; ++ks2) {
            const int kk8 = ks2 * 2 + h32;
            bf16x8 af[2], bfr[2];
            af[0]  = *(bf16x8*)&As[p][(kk8 * 128 + wm * 64 + (lane & 31)) * 8];
            af[1]  = *(bf16x8*)&As[p][(kk8 * 128 + wm * 64 + 32 + (lane & 31)) * 8];
            bfr[0] = *(bf16x8*)&Bs[p][(kk8 * 128 + wn * 64 + (lane & 31)) * 8];
            bfr[1] = *(bf16x8*)&Bs[p][(kk8 * 128 + wn * 64 + 32 + (lane & 31)) * 8];
            acc[0][0] = __builtin_amdgcn_mfma_f32_32x32x16_bf16(af[0], bfr[0], acc[0][0], 0, 0, 0);
            acc[0][1] = __builtin_amdgcn_mfma_f32_32x32x16_bf16(af[0], bfr[1], acc[0][1], 0, 0, 0);
            acc[1][0] = __builtin_amdgcn_mfma_f32_32x32x16_bf16(af[1], bfr[0], acc[1][0], 0, 0, 0);
            acc[1][1] = __builtin_amdgcn_mfma_f32_32x32x16_bf16(af[1], bfr[1], acc[1][1], 0, 0, 0);
        }
        __syncthreads();   // waits prefetch DMA (issued ~1 compute-block ago) + LDS reads
        p ^= 1;
    }

    #pragma unroll
    for (int mt = 0; mt < 2; ++mt) {
        #pragma unroll
        for (int nt = 0; nt < 2; ++nt) {
            const int rbase = m0 + wm * 64 + mt * 32;
            const int col   = n0 + wn * 64 + nt * 32 + (lane & 31);
            float bv = 0.f;
            if (!OUT_BF16 && bias) bv = bias[col];
            #pragma unroll
            for (int r = 0; r < 16; ++r) {
                int row = rbase + (r & 3) + 8 * (r >> 2) + 4 * h32;
                if constexpr (OUT_BF16)
                    ((short*)Cv)[(size_t)row * N + col] = f2bf(acc[mt][nt][r] * oscale);
                else
                    ((float*)Cv)[(size_t)row * N + col] = acc[mt][nt][r] + bv;
            }
        }
    }
}

// ---------------- MFMA attention v4: no LDS, no barriers --------------------
// 4 waves x 64 t-rows = 256 t/block. K-frags straight from q (b128, L1-shared
// across waves); V-frags straight from qT (pi baked -> contiguous b128).
// q pre-scaled by c = sqrt(0.125*log2e): exp = bare v_exp_f32; output
// compensated by 1/c (and P-truncation bias) in inv.
__global__ __launch_bounds__(256, 2) void attn_mfma(const short* __restrict__ q,
                                                    const short* __restrict__ qT,
                                                    short* __restrict__ o) {
    const int tid  = threadIdx.x;
    const int lane = tid & 63;
    const int wv   = tid >> 6;
    const int h32  = lane >> 5;
    const int l31  = lane & 31;
    const int bh = blockIdx.y;
    const int b  = bh >> 4, hh = bh & 15;
    const int t0 = blockIdx.x * 256;
    const short* qh = q + (size_t)b * (T_ * D_) + hh * S_;
    const short* qr = qT + (size_t)bh * S_ * T_;

    bf16x8 Qreg[2][4];
    #pragma unroll
    for (int g = 0; g < 2; ++g) {
        int tq = t0 + wv * 64 + g * 32 + l31;
        #pragma unroll
        for (int ks = 0; ks < 4; ++ks)
            Qreg[g][ks] = *(const bf16x8*)(qh + (size_t)tq * D_ + (2 * ks + h32) * 8);
    }

    f32x16 accO[2][2];
    #pragma unroll
    for (int g = 0; g < 2; ++g)
        #pragma unroll
        for (int s = 0; s < 2; ++s)
            #pragma unroll
            for (int r = 0; r < 16; ++r) accO[g][s][r] = 0.f;
    float lsa[2] = {0.f, 0.f}, lsb[2] = {0.f, 0.f};

    #pragma unroll 1
    for (int u0 = 0; u0 < T_; u0 += 64) {
        bf16x8 Kf[2][4], Vf[4][2];
        #pragma unroll
        for (int kh = 0; kh < 2; ++kh) {
            int u = u0 + kh * 32 + l31;
            #pragma unroll
            for (int ks = 0; ks < 4; ++ks)
                Kf[kh][ks] = *(const bf16x8*)(qh + (size_t)u * D_ + (2 * ks + h32) * 8);
        }
        #pragma unroll
        for (int c = 0; c < 4; ++c)
            #pragma unroll
            for (int sh = 0; sh < 2; ++sh)
                Vf[c][sh] = *(const bf16x8*)(qr + (size_t)(sh * 32 + l31) * T_
                                             + u0 + c * 16 + h32 * 8);

        #pragma unroll
        for (int g = 0; g < 2; ++g) {
            f32x16 aS0, aS1;
            #pragma unroll
            for (int i = 0; i < 16; ++i) { aS0[i] = 0.f; aS1[i] = 0.f; }
            #pragma unroll
            for (int ks = 0; ks < 4; ++ks) {
                aS0 = __builtin_amdgcn_mfma_f32_32x32x16_bf16(Kf[0][ks], Qreg[g][ks], aS0, 0, 0, 0);
                aS1 = __builtin_amdgcn_mfma_f32_32x32x16_bf16(Kf[1][ks], Qreg[g][ks], aS1, 0, 0, 0);
            }
            bf16x8 af[4];
            #pragma unroll
            for (int kh = 0; kh < 2; ++kh) {
                const f32x16& a = kh ? aS1 : aS0;
                float p[16];
                #pragma unroll
                for (int r = 0; r < 16; ++r) {
                    p[r] = __builtin_amdgcn_exp2f(a[r]);   // scale folded into q
                    if (r & 1) lsb[g] += p[r]; else lsa[g] += p[r];
                }
                #pragma unroll
                for (int sub = 0; sub < 2; ++sub) {
                    union { uint u[4]; bf16x8 v; } cv;
                    #pragma unroll
                    for (int dd = 0; dd < 4; ++dd)
                        cv.u[dd] = __builtin_amdgcn_perm(
                            __float_as_uint(p[sub * 8 + 2 * dd + 1]),
                            __float_as_uint(p[sub * 8 + 2 * dd]), 0x07060302u);
                    af[kh * 2 + sub] = cv.v;
                }
            }
            #pragma unroll
            for (int c = 0; c < 4; ++c) {
                accO[g][0] = __builtin_amdgcn_mfma_f32_32x32x16_bf16(af[c], Vf[c][0], accO[g][0], 0, 0, 0);
                accO[g][1] = __builtin_amdgcn_mfma_f32_32x32x16_bf16(af[c], Vf[c][1], accO[g][1], 0, 0, 0);
            }
        }
    }

    short* ob = o + (size_t)b * (T_ * D_) + hh * S_;
    #pragma unroll
    for (int g = 0; g < 2; ++g) {
        float ds = lsa[g] + lsb[g];
        ds += __shfl_xor(ds, 32);
        #pragma unroll
        for (int r = 0; r < 16; ++r) {
            int rt = (r & 3) + 8 * (r >> 2) + 4 * h32;
            float inv = 2.3594089f / __shfl(ds, rt);      // 1/c * 1.00195
            size_t t = (size_t)(t0 + wv * 64 + g * 32 + rt);
            ob[t * D_ + l31]      = f2bf(accO[g][0][r] * inv);
            ob[t * D_ + 32 + l31] = f2bf(accO[g][1][r] * inv);
        }
    }
}

extern "C" void kernel_launch(void* const* d_in, const int* in_sizes, int n_in,
                              void* d_out, int out_size, void* d_ws, size_t ws_size,
                              hipStream_t stream) {
    const float* x  = (const float*)d_in[0];
    const float* Wq = (const float*)d_in[1];
    const float* Wu = (const float*)d_in[2];
    const float* bu = (const float*)d_in[3];
    float* out  = (float*)d_out;
    short* qbuf = (short*)d_out;                          // bf16 q (scaled), [0,16.8M)
    short* xb   = (short*)((char*)d_out + 16777216);      // bf16 x, dead after gemm1
    short* qT   = xb;                                     // qT reuses xb space
    short* attn = (short*)d_ws;                           // bf16 attn out (16.8 MB)
    short* wqb  = (short*)((char*)d_ws + 16777216);       // bf16 Wq (2 MB)
    short* wub  = (short*)((char*)d_ws + 18874368);       // bf16 Wu (2 MB)

    const int M = B_ * T_;
    dim3 blk(256);
    dim3 gg(D_ / 128, M / 128);
    // 0) bf16 conversions
    hipLaunchKernelGGL(cvt3, dim3(5120), blk, 0, stream, x, Wq, Wu, xb, wqb, wub);
    // 1) q = (x @ Wq^T) * c,  c = sqrt(0.125*log2e)  -> exp2 needs no mul
    hipLaunchKernelGGL((gemm_bt<true>), gg, blk, 0, stream,
                       xb, wqb, (const float*)nullptr, (void*)qbuf, M, D_, D_, 0.42466090f);
    // 1b) qT[bh][s][t] = q (pi-permuted t), for contiguous PV B-fragments
    hipLaunchKernelGGL(transp, dim3(T_ / 64, B_ * H_), blk, 0, stream, qbuf, qT);
    // 2) attn = softmax-ish(q q^T) q   — LDS-free MFMA kernel
    hipLaunchKernelGGL(attn_mfma, dim3(T_ / 256, B_ * H_), blk, 0, stream, qbuf, qT, attn);
    // 3) out = attn @ Wu^T + bu  (fp32)
    hipLaunchKernelGGL((gemm_bt<false>), gg, blk, 0, stream,
                       attn, wub, bu, (void*)out, M, D_, D_, 1.0f);
}